// Round 3
// baseline (385.816 us; speedup 1.0000x reference)
//
#include <hip/hip_runtime.h>
#include <hip/hip_fp16.h>

// Fused 8-step diffusion: one block per (n,c) plane (256 blocks = 1/CU).
// Each of 512 threads owns an 8-row x 4-col patch of x in registers and its
// 8x9x4 normalized |w| weights as fp16 registers (144 VGPRs), loaded from HBM
// exactly once. Row halos via 16KB LDS, column halos via wave shuffles.
// NOTE: no address-taken arrays anywhere — every array index is a constant
// after unrolling, so everything SROA-promotes to registers (round-2 version
// spilled ~450MB to scratch via a pointer array; VGPR=64 + WRITE_SIZE=163MB).

constexpr int H = 128, W = 128, PLANE = H * W;
constexpr int NSTEP = 8;
constexpr int RPT = 8;            // rows per thread
constexpr int NRG = H / RPT;      // 16 row-groups

// build 6-wide column window (cols j0-1 .. j0+4) from a float4 row segment
#define MKWIN(D, V) do {                                                     \
    (D)[1] = (V).x; (D)[2] = (V).y; (D)[3] = (V).z; (D)[4] = (V).w;          \
    float _l = __shfl_up((V).w, 1);                                          \
    float _r = __shfl_down((V).x, 1);                                        \
    (D)[0] = (quad == 0)  ? 0.f : _l;                                        \
    (D)[5] = (quad == 31) ? 0.f : _r;                                        \
} while (0)

__global__ __launch_bounds__(512, 2)
void diff_fused(const float* __restrict__ xin,
                const float* __restrict__ wgt,
                float* __restrict__ out)
{
    __shared__ float ldsT[NRG][W];   // top row (r0)    of each row-group
    __shared__ float ldsB[NRG][W];   // bottom row (r0+7)

    const int tid  = threadIdx.x;
    const int quad = tid & 31;       // column quad: cols 4q..4q+3
    const int rg   = tid >> 5;       // row-group 0..15
    const int j0   = quad * 4;
    const int r0   = rg * RPT;
    const size_t pbase = (size_t)blockIdx.x * PLANE;

    const float* __restrict__ xp = xin + pbase;
    const float* __restrict__ wb = wgt + pbase * 9;   // (n*576+c*9)*PLANE

    // ---- x patch into registers ----
    float4 xr[RPT];
    #pragma unroll
    for (int p = 0; p < RPT; ++p)
        xr[p] = *reinterpret_cast<const float4*>(xp + (r0 + p) * W + j0);

    // ---- weights: load once, |.|-normalize fp32, hold as fp16 regs ----
    __half2 wh[RPT][9][2];           // 144 VGPRs
    #pragma unroll
    for (int p = 0; p < RPT; ++p) {
        float a[9][4];
        float s0 = 0.f, s1 = 0.f, s2 = 0.f, s3 = 0.f;
        #pragma unroll
        for (int k = 0; k < 9; ++k) {
            float4 v = *reinterpret_cast<const float4*>(
                wb + (size_t)k * PLANE + (r0 + p) * W + j0);
            a[k][0] = fabsf(v.x); a[k][1] = fabsf(v.y);
            a[k][2] = fabsf(v.z); a[k][3] = fabsf(v.w);
            s0 += a[k][0]; s1 += a[k][1]; s2 += a[k][2]; s3 += a[k][3];
        }
        s0 = 1.f / s0; s1 = 1.f / s1; s2 = 1.f / s2; s3 = 1.f / s3;
        #pragma unroll
        for (int k = 0; k < 9; ++k) {
            wh[p][k][0] = __halves2half2(__float2half_rn(a[k][0] * s0),
                                         __float2half_rn(a[k][1] * s1));
            wh[p][k][1] = __halves2half2(__float2half_rn(a[k][2] * s2),
                                         __float2half_rn(a[k][3] * s3));
        }
    }

    // ---- 8 fused steps, zero global traffic ----
    for (int s = 0; s < NSTEP; ++s) {
        *reinterpret_cast<float4*>(&ldsT[rg][j0]) = xr[0];
        *reinterpret_cast<float4*>(&ldsB[rg][j0]) = xr[RPT - 1];
        __syncthreads();
        float4 up = make_float4(0.f, 0.f, 0.f, 0.f);   // global row r0-1
        float4 dn = make_float4(0.f, 0.f, 0.f, 0.f);   // global row r0+8
        if (rg > 0)       up = *reinterpret_cast<const float4*>(&ldsB[rg - 1][j0]);
        if (rg < NRG - 1) dn = *reinterpret_cast<const float4*>(&ldsT[rg + 1][j0]);
        __syncthreads();   // reads done before next step's writes

        // rotating 3-row window file; all indices constant after unroll
        float win[3][6];
        MKWIN(win[0], up);       // input row r0-1
        MKWIN(win[1], xr[0]);    // input row r0
        #pragma unroll
        for (int p = 0; p < RPT; ++p) {
            if (p < RPT - 1) { MKWIN(win[(p + 2) % 3], xr[p + 1]); }
            else             { MKWIN(win[(p + 2) % 3], dn); }
            float a0 = 0.f, a1 = 0.f, a2 = 0.f, a3 = 0.f;
            #pragma unroll
            for (int di = 0; di < 3; ++di) {
                #pragma unroll
                for (int dj = 0; dj < 3; ++dj) {
                    const int k = di * 3 + dj;
                    a0 = fmaf(__low2float (wh[p][k][0]), win[(p + di) % 3][dj + 0], a0);
                    a1 = fmaf(__high2float(wh[p][k][0]), win[(p + di) % 3][dj + 1], a1);
                    a2 = fmaf(__low2float (wh[p][k][1]), win[(p + di) % 3][dj + 2], a2);
                    a3 = fmaf(__high2float(wh[p][k][1]), win[(p + di) % 3][dj + 3], a3);
                }
            }
            xr[p] = make_float4(a0, a1, a2, a3);   // old xr[p] fully consumed
        }
    }

    // ---- store (coalesced float4) ----
    float* __restrict__ op = out + pbase;
    #pragma unroll
    for (int p = 0; p < RPT; ++p)
        *reinterpret_cast<float4*>(op + (r0 + p) * W + j0) = xr[p];
}

extern "C" void kernel_launch(void* const* d_in, const int* in_sizes, int n_in,
                              void* d_out, int out_size, void* d_ws, size_t ws_size,
                              hipStream_t stream)
{
    const float* x = (const float*)d_in[0];
    const float* w = (const float*)d_in[1];
    float* out = (float*)d_out;
    (void)d_ws; (void)ws_size; (void)in_sizes; (void)n_in; (void)out_size;

    diff_fused<<<dim3(4 * 64), dim3(512), 0, stream>>>(x, w, out);
}